// Round 1
// baseline (1092.528 us; speedup 1.0000x reference)
//
#include <hip/hip_runtime.h>
#include <math.h>

#define N_NODES 51200
#define N_EDGES 640000
#define N_TYPES 4
#define N_RELS  8
#define N_HEADS 4
#define D_K     32
#define DIM     128
#define NODES_PER_TYPE (N_NODES / N_TYPES)   // 12800
#define EDGES_PER_REL  (N_EDGES / N_RELS)    // 80000
#define INV_SQRT_DK 0.17677669529663687f

__global__ __launch_bounds__(256) void zero_kernel(float* __restrict__ p, int n4) {
    int i = blockIdx.x * blockDim.x + threadIdx.x;
    if (i < n4) ((float4*)p)[i] = make_float4(0.f, 0.f, 0.f, 0.f);
}

// Per-node-type projection GEMM: out[n][o] = sum_d x[n][d] * W[type(n)][d][o]
// grid.x = N/64 node blocks, grid.y = 3 selects (k,q,v)
__global__ __launch_bounds__(256) void proj_kernel(
    const float* __restrict__ h,
    const float* __restrict__ Wk,
    const float* __restrict__ Wq,
    const float* __restrict__ Wv,
    float* __restrict__ kf, float* __restrict__ qf, float* __restrict__ vf)
{
    __shared__ float hs[64][132];   // +4 pad: float4-aligned rows, 2-way-max bank aliasing
    const int tid = threadIdx.x;
    const int which = blockIdx.y;
    const float* W = (which == 0) ? Wk : (which == 1) ? Wq : Wv;
    float* outp    = (which == 0) ? kf : (which == 1) ? qf : vf;
    const int n0 = blockIdx.x * 64;
    const int t = n0 / NODES_PER_TYPE;
    const float* Wt = W + (size_t)t * DIM * DIM;

    const float4* hsrc = (const float4*)(h + (size_t)n0 * DIM);
    #pragma unroll
    for (int i = 0; i < 8; ++i) {
        int f = tid + i * 256;
        int row = f >> 5, c4 = f & 31;
        *(float4*)&hs[row][c4 * 4] = hsrc[f];
    }
    __syncthreads();

    const int ty = tid >> 4, tx = tid & 15;   // 16x16 threads: 4 nodes x 8 outs each
    float acc[4][8];
    #pragma unroll
    for (int i = 0; i < 4; ++i)
        #pragma unroll
        for (int j = 0; j < 8; ++j) acc[i][j] = 0.f;

    #pragma unroll 2
    for (int d = 0; d < DIM; ++d) {
        const float* wrow = Wt + d * DIM + tx * 8;
        float4 w0 = *(const float4*)wrow;
        float4 w1 = *(const float4*)(wrow + 4);
        float hv[4];
        #pragma unroll
        for (int i = 0; i < 4; ++i) hv[i] = hs[ty * 4 + i][d];
        #pragma unroll
        for (int i = 0; i < 4; ++i) {
            acc[i][0] = fmaf(hv[i], w0.x, acc[i][0]);
            acc[i][1] = fmaf(hv[i], w0.y, acc[i][1]);
            acc[i][2] = fmaf(hv[i], w0.z, acc[i][2]);
            acc[i][3] = fmaf(hv[i], w0.w, acc[i][3]);
            acc[i][4] = fmaf(hv[i], w1.x, acc[i][4]);
            acc[i][5] = fmaf(hv[i], w1.y, acc[i][5]);
            acc[i][6] = fmaf(hv[i], w1.z, acc[i][6]);
            acc[i][7] = fmaf(hv[i], w1.w, acc[i][7]);
        }
    }
    #pragma unroll
    for (int i = 0; i < 4; ++i) {
        float* orow = outp + (size_t)(n0 + ty * 4 + i) * DIM + tx * 8;
        *(float4*)orow       = make_float4(acc[i][0], acc[i][1], acc[i][2], acc[i][3]);
        *(float4*)(orow + 4) = make_float4(acc[i][4], acc[i][5], acc[i][6], acc[i][7]);
    }
}

// Edge attention scores: score[e][h] = (q[col[e]][h] @ Watt[r][h]) . k[row[e]][h] * pri
// Fused exp + denominator atomicAdd (segment-max skipped: exact softmax invariance,
// |score| < ~1, no overflow risk).
// 128 edges/block (single relation per block), thread = (slot, head, d).
__global__ __launch_bounds__(256) void score_kernel(
    const float* __restrict__ qf, const float* __restrict__ kf,
    const float* __restrict__ Watt, const float* __restrict__ pri,
    const int* __restrict__ row_idx, const int* __restrict__ col_idx,
    float* __restrict__ evals, float* __restrict__ denom)
{
    const int tid  = threadIdx.x;
    const int slot = tid >> 7;        // 0/1: two edges in flight
    const int rem  = tid & 127;
    const int hh   = rem >> 5;
    const int d    = rem & 31;
    const int eb   = blockIdx.x * 128;
    const int r    = eb / EDGES_PER_REL;

    // W_att column [k][d] into registers, reused for all 128 edges
    const float* Wbase = Watt + ((size_t)r * N_HEADS + hh) * D_K * D_K + d;
    float wcol[32];
    #pragma unroll
    for (int k = 0; k < 32; ++k) wcol[k] = Wbase[k * 32];
    const float prih = pri[r * N_HEADS + hh] * INV_SQRT_DK;

    for (int p = 0; p < 64; ++p) {
        const int e = eb + p * 2 + slot;
        const int src = row_idx[e];
        const int dst = col_idx[e];
        const float q_own = qf[(size_t)dst * DIM + rem];
        const float k_own = kf[(size_t)src * DIM + rem];
        float aw = 0.f;
        #pragma unroll
        for (int k = 0; k < 32; ++k)
            aw = fmaf(__shfl(q_own, k, 32), wcol[k], aw);
        float part = aw * k_own;
        #pragma unroll
        for (int off = 16; off > 0; off >>= 1)
            part += __shfl_xor(part, off, 32);
        if (d == 0) {
            float ev = expf(part * prih);
            evals[e * 4 + hh] = ev;
            atomicAdd(&denom[dst * 4 + hh], ev);
        }
    }
}

// Messages + softmax-weighted aggregation:
// agg[col[e]][h][d] += (ev/denom) * sum_k v[row[e]][h][k] * Wmsg[r][h][k][d]
__global__ __launch_bounds__(256) void msg_kernel(
    const float* __restrict__ vf,
    const float* __restrict__ Wmsg,
    const int* __restrict__ row_idx, const int* __restrict__ col_idx,
    const float* __restrict__ evals, const float* __restrict__ denom,
    float* __restrict__ agg)
{
    const int tid  = threadIdx.x;
    const int slot = tid >> 7;
    const int rem  = tid & 127;
    const int hh   = rem >> 5;
    const int d    = rem & 31;
    const int eb   = blockIdx.x * 128;
    const int r    = eb / EDGES_PER_REL;

    const float* Wbase = Wmsg + ((size_t)r * N_HEADS + hh) * D_K * D_K + d;
    float wcol[32];
    #pragma unroll
    for (int k = 0; k < 32; ++k) wcol[k] = Wbase[k * 32];

    for (int p = 0; p < 64; ++p) {
        const int e = eb + p * 2 + slot;
        const int src = row_idx[e];
        const int dst = col_idx[e];
        const float v_own = vf[(size_t)src * DIM + rem];
        float ms = 0.f;
        #pragma unroll
        for (int k = 0; k < 32; ++k)
            ms = fmaf(__shfl(v_own, k, 32), wcol[k], ms);
        const float alpha = evals[e * 4 + hh] / (denom[dst * 4 + hh] + 1e-16f);
        atomicAdd(&agg[(size_t)dst * DIM + rem], alpha * ms);
    }
}

// Output projection with per-type sigmoid(skip) gate
__global__ __launch_bounds__(256) void out_kernel(
    const float* __restrict__ agg,
    const float* __restrict__ A,
    const float* __restrict__ skip,
    float* __restrict__ outp)
{
    __shared__ float hs[64][132];
    const int tid = threadIdx.x;
    const int n0 = blockIdx.x * 64;
    const int t = n0 / NODES_PER_TYPE;
    const float* Wt = A + (size_t)t * DIM * DIM;
    const float sg = 1.f / (1.f + expf(-skip[t]));

    const float4* hsrc = (const float4*)(agg + (size_t)n0 * DIM);
    #pragma unroll
    for (int i = 0; i < 8; ++i) {
        int f = tid + i * 256;
        int row = f >> 5, c4 = f & 31;
        *(float4*)&hs[row][c4 * 4] = hsrc[f];
    }
    __syncthreads();

    const int ty = tid >> 4, tx = tid & 15;
    float acc[4][8];
    #pragma unroll
    for (int i = 0; i < 4; ++i)
        #pragma unroll
        for (int j = 0; j < 8; ++j) acc[i][j] = 0.f;

    #pragma unroll 2
    for (int d = 0; d < DIM; ++d) {
        const float* wrow = Wt + d * DIM + tx * 8;
        float4 w0 = *(const float4*)wrow;
        float4 w1 = *(const float4*)(wrow + 4);
        float hv[4];
        #pragma unroll
        for (int i = 0; i < 4; ++i) hv[i] = hs[ty * 4 + i][d];
        #pragma unroll
        for (int i = 0; i < 4; ++i) {
            acc[i][0] = fmaf(hv[i], w0.x, acc[i][0]);
            acc[i][1] = fmaf(hv[i], w0.y, acc[i][1]);
            acc[i][2] = fmaf(hv[i], w0.z, acc[i][2]);
            acc[i][3] = fmaf(hv[i], w0.w, acc[i][3]);
            acc[i][4] = fmaf(hv[i], w1.x, acc[i][4]);
            acc[i][5] = fmaf(hv[i], w1.y, acc[i][5]);
            acc[i][6] = fmaf(hv[i], w1.z, acc[i][6]);
            acc[i][7] = fmaf(hv[i], w1.w, acc[i][7]);
        }
    }
    #pragma unroll
    for (int i = 0; i < 4; ++i) {
        float* orow = outp + (size_t)(n0 + ty * 4 + i) * DIM + tx * 8;
        *(float4*)orow       = make_float4(sg*acc[i][0], sg*acc[i][1], sg*acc[i][2], sg*acc[i][3]);
        *(float4*)(orow + 4) = make_float4(sg*acc[i][4], sg*acc[i][5], sg*acc[i][6], sg*acc[i][7]);
    }
}

extern "C" void kernel_launch(void* const* d_in, const int* in_sizes, int n_in,
                              void* d_out, int out_size, void* d_ws, size_t ws_size,
                              hipStream_t stream) {
    (void)in_sizes; (void)n_in; (void)out_size; (void)ws_size;
    const float* h    = (const float*)d_in[0];
    const float* Wk   = (const float*)d_in[1];
    const float* Wq   = (const float*)d_in[2];
    const float* Wv   = (const float*)d_in[3];
    const float* Wa   = (const float*)d_in[4];
    const float* Watt = (const float*)d_in[5];
    const float* Wmsg = (const float*)d_in[6];
    const float* pri  = (const float*)d_in[7];
    const float* skip = (const float*)d_in[8];
    const int* row_idx = (const int*)d_in[9];
    const int* col_idx = (const int*)d_in[10];

    float* out = (float*)d_out;
    float* ws  = (float*)d_ws;

    // ws layout: [kf | qf | vf], 3 * N*128 floats = 78.6 MB.
    // agg overlays kf (kf is dead after score_kernel).
    // evals (E*4) + denom (N*4) staged at the front of d_out (overwritten by out_kernel).
    float* kf = ws;
    float* qf = ws + (size_t)N_NODES * DIM;
    float* vf = ws + (size_t)2 * N_NODES * DIM;
    float* agg = kf;
    float* evals = out;
    float* denom = out + (size_t)N_EDGES * N_HEADS;

    // 1. zero softmax denominators (must precede score_kernel atomics)
    zero_kernel<<<(N_NODES * N_HEADS / 4 + 255) / 256, 256, 0, stream>>>(denom, N_NODES * N_HEADS / 4);
    // 2. K/Q/V projections
    proj_kernel<<<dim3(N_NODES / 64, 3), 256, 0, stream>>>(h, Wk, Wq, Wv, kf, qf, vf);
    // 3. edge scores -> exp + denominator
    score_kernel<<<N_EDGES / 128, 256, 0, stream>>>(qf, kf, Watt, pri, row_idx, col_idx, evals, denom);
    // 4. zero agg (reuses kf space — only after kf consumed)
    zero_kernel<<<(N_NODES * DIM / 4 + 255) / 256, 256, 0, stream>>>(agg, N_NODES * DIM / 4);
    // 5. messages + weighted aggregation
    msg_kernel<<<N_EDGES / 128, 256, 0, stream>>>(vf, Wmsg, row_idx, col_idx, evals, denom, agg);
    // 6. output projection
    out_kernel<<<N_NODES / 64, 256, 0, stream>>>(agg, Wa, skip, out);
}